// Round 4
// baseline (60.214 us; speedup 1.0000x reference)
//
#include <hip/hip_runtime.h>
#include <math.h>

// Problem constants (match reference setup_inputs)
constexpr int B = 32;
constexpr int C = 1024;
constexpr int T = 1024;
constexpr int N = 3;
constexpr int CPB = 32;          // channels per block -> grid = 32*32 = 1024
constexpr int NSTAGE = CPB / 4;  // 8 stages; each stage = 1 channel per wave

__device__ __forceinline__ float wred(float x) {
#pragma unroll
  for (int off = 32; off > 0; off >>= 1) x += __shfl_down(x, off);
  return x;
}

__device__ __forceinline__ float dot4(const float4 a, const float4 b) {
  return a.x * b.x + a.y * b.y + a.z * b.z + a.w * b.w;
}

__device__ __forceinline__ void waitv4() {
  asm volatile("s_waitcnt vmcnt(4)" ::: "memory");
}
__device__ __forceinline__ void waitv0() {
  asm volatile("s_waitcnt vmcnt(0)" ::: "memory");
}

// ---------------------------------------------------------------------------
// Fully fused, barrier-free kernel.
//   * grid = 1024 blocks (exactly 4/CU), 256 threads; each wave owns 8
//     channel rows of one batch.
//   * video rows are staged via global_load_lds (16 B/lane, zero VGPR cost)
//     into a per-wave private 2-deep double buffer -> each wave runs its own
//     software pipeline with counted s_waitcnt vmcnt(4); NO __syncthreads
//     anywhere (no cross-wave LDS sharing), so waves free-run and the
//     barrier-drain stall (vmcnt(0) before s_barrier) never happens.
//   * unnormalized Cauchy weights u = 1/(1+d^2) live in 48 VGPRs per lane
//     (lane always consumes t-positions 4*(lane+64k)+j); normalization is
//     deferred algebraically to the epilogue: o = pref*dot /(pref*sum+1e-6).
//   * epilogue: 27 independent wave shuffle reductions, lane 0 stores.
// ---------------------------------------------------------------------------
__global__ __launch_bounds__(256, 4) void tsf_fused(
    const float* __restrict__ v /* [B][C][T] */,
    const int* __restrict__ length,
    const float* __restrict__ center,
    const float* __restrict__ gamma_,
    float* __restrict__ out /* [B][C][N] */) {
  const int b = blockIdx.x >> 5;        // 32 channel-groups per batch
  const int cg = blockIdx.x & 31;
  const int lane = threadIdx.x & 63;
  const int wv = threadIdx.x >> 6;
  const int ch_base = cg * CPB;         // + s*4 + wv per stage

  // [dbuf][wave][t] -- each wave touches ONLY its own [.][wv][.] slice
  __shared__ float buf[2][4][T];        // 32 KB

  const float* vbase = v + (size_t)b * C * T;

  // issue 4x global_load_lds (16 B each) for stage s's channel of this wave
  auto stage_issue = [&](int s) {
    const int ch = ch_base + s * 4 + wv;
    const float* row = vbase + (size_t)ch * T;
    float* ldsrow = &buf[s & 1][wv][0];
#pragma unroll
    for (int it = 0; it < 4; ++it) {
      __builtin_amdgcn_global_load_lds(
          (const __attribute__((address_space(1))) void*)(row +
                                                          4 * (lane + 64 * it)),
          (__attribute__((address_space(3))) void*)(ldsrow +
                                                    4 * (lane + 64 * it)),
          16, 0, 0);
    }
  };

  // ---- prologue: fill the 2-deep pipeline, then compute weights under it
  stage_issue(0);
  stage_issue(1);

  const float lf = (float)length[b];
  float4 w[N][4];
  float s_[N];
  float pref[N];
#pragma unroll
  for (int n = 0; n < N; ++n) {
    const float c = tanhf(center[n]);
    const float g = tanhf(gamma_[n]);
    const float ctr = (lf - 1.0f) * (c + 1.0f) * 0.5f;
    const float gam = expf(1.5f - 2.0f * fabsf(g));
    const float a = 1.0f / gam;  // d = t*a + bb
    const float bb = -ctr * a;
    pref[n] = 1.0f / (3.14159265358979f * gam);
    s_[n] = 0.0f;
#pragma unroll
    for (int k = 0; k < 4; ++k) {
      const float t0 = (float)(4 * lane + 256 * k);
      float4 wk;
      float d;
      d = fmaf(t0 + 0.0f, a, bb); wk.x = 1.0f / fmaf(d, d, 1.0f);
      d = fmaf(t0 + 1.0f, a, bb); wk.y = 1.0f / fmaf(d, d, 1.0f);
      d = fmaf(t0 + 2.0f, a, bb); wk.z = 1.0f / fmaf(d, d, 1.0f);
      d = fmaf(t0 + 3.0f, a, bb); wk.w = 1.0f / fmaf(d, d, 1.0f);
      w[n][k] = wk;
      s_[n] += (wk.x + wk.y) + (wk.z + wk.w);
    }
  }

  // ---- main pipeline: 8 stages, per-wave private, counted vmcnt ----
  float acc[NSTAGE][N];
#pragma unroll
  for (int s = 0; s < NSTAGE; ++s) {
    if (s < NSTAGE - 1) waitv4();  // this stage's 4 loads retired
    else waitv0();                 // final drain
    const float4* src = (const float4*)&buf[s & 1][wv][0];
    const float4 x0 = src[lane];
    const float4 x1 = src[lane + 64];
    const float4 x2 = src[lane + 128];
    const float4 x3 = src[lane + 192];
#pragma unroll
    for (int n = 0; n < N; ++n)
      acc[s][n] = dot4(x0, w[n][0]) + dot4(x1, w[n][1]) +
                  dot4(x2, w[n][2]) + dot4(x3, w[n][3]);
    if (s + 2 < NSTAGE) stage_issue(s + 2);  // refill own slice (2-deep)
  }

  // ---- epilogue: 27 independent wave reductions, lane 0 stores ----
#pragma unroll
  for (int s = 0; s < NSTAGE; ++s)
#pragma unroll
    for (int n = 0; n < N; ++n) acc[s][n] = wred(acc[s][n]);
#pragma unroll
  for (int n = 0; n < N; ++n) s_[n] = wred(s_[n]);

  if (lane == 0) {
#pragma unroll
    for (int n = 0; n < N; ++n) {
      const float scale = pref[n] / fmaf(pref[n], s_[n], 1e-6f);
#pragma unroll
      for (int s = 0; s < NSTAGE; ++s) {
        const int ch = ch_base + s * 4 + wv;
        out[((size_t)b * C + ch) * N + n] = acc[s][n] * scale;
      }
    }
  }
}

// ---------------------------------------------------------------------------
extern "C" void kernel_launch(void* const* d_in, const int* in_sizes, int n_in,
                              void* d_out, int out_size, void* d_ws,
                              size_t ws_size, hipStream_t stream) {
  const float* video = (const float*)d_in[0];   // (B, C, T, 1, 1) fp32
  const int* length = (const int*)d_in[1];      // (B,) int32
  const float* center = (const float*)d_in[2];  // (N,) fp32
  // d_in[3] = delta (unused by reference)
  const float* gamma_ = (const float*)d_in[4];  // (N,) fp32
  float* out = (float*)d_out;                   // (B, C*N) fp32

  tsf_fused<<<B * (C / CPB), 256, 0, stream>>>(video, length, center, gamma_,
                                               out);
}

// Round 5
// 35.762 us; speedup vs baseline: 1.6837x; 1.6837x over previous
//
#include <hip/hip_runtime.h>
#include <math.h>

// Problem constants (match reference setup_inputs)
constexpr int B = 32;
constexpr int C = 1024;
constexpr int T = 1024;
constexpr int N = 3;
constexpr int CPB = 16;  // channels per block -> grid = 32*64 = 2048 = 8/CU
constexpr int CPW = 4;   // channels per wave

typedef float f4 __attribute__((ext_vector_type(4)));

__device__ __forceinline__ float wred(float x) {
#pragma unroll
  for (int off = 32; off > 0; off >>= 1) x += __shfl_down(x, off);
  return x;
}

__device__ __forceinline__ float dot4(const f4 a, const f4 b) {
  return a.x * b.x + a.y * b.y + a.z * b.z + a.w * b.w;
}

// ---------------------------------------------------------------------------
// Fused kernel, round-2 skeleton + 3 edits:
//   * block = (batch, 16-channel group); whole grid (2048 blocks) co-resident
//     at 8 blocks/CU, so the redundant weight prologue costs ~1 us once.
//   * prologue: block computes normalized f[b][3][1024] into LDS (12 KB).
//   * main: each wave owns 4 channel rows; ALL 16 float4 loads issued
//     up-front as NONTEMPORAL loads (zero-reuse data, skip L2 retention;
//     16 KB/wave in flight -> latency fully hidden).
//   * weights read from LDS once per k-chunk (12 ds_read_b128/wave total).
//   * ALL shuffle reductions deferred to a single epilogue (12 wred).
// No __launch_bounds__ min-waves forcing (round-4 lesson: it caused scratch
// spill -> 89 MB of HBM write traffic). VGPR ~110 -> 4 blocks/CU minimum.
// ---------------------------------------------------------------------------
__global__ __launch_bounds__(256) void tsf_fused(
    const float* __restrict__ v /* [B][C][T] */,
    const int* __restrict__ length,
    const float* __restrict__ center,
    const float* __restrict__ gamma_,
    float* __restrict__ out /* [B][C][N] */) {
  const int groups_per_b = C / CPB;
  const int b = blockIdx.x / groups_per_b;
  const int cg = blockIdx.x % groups_per_b;
  const int lane = threadIdx.x & 63;
  const int wv = threadIdx.x >> 6;

  __shared__ float fs[N][T];    // 12 KB normalized weights
  __shared__ float wsumS[N][4];

  // ---- weight prologue (identical math to round 2) ----
  const float lf = (float)length[b];
  float vals[N][4];
#pragma unroll
  for (int n = 0; n < N; ++n) {
    const float c = tanhf(center[n]);
    const float g = tanhf(gamma_[n]);
    const float ctr = (lf - 1.0f) * (c + 1.0f) * 0.5f;
    const float gam = expf(1.5f - 2.0f * fabsf(g));
    const float inv_gam = 1.0f / gam;
    const float pref = 1.0f / (3.14159265358979f * gam);

    float s = 0.0f;
#pragma unroll
    for (int i = 0; i < 4; ++i) {
      const float t = (float)(threadIdx.x + i * 256);
      const float d = (t - ctr) * inv_gam;
      vals[n][i] = pref / fmaf(d, d, 1.0f);
      s += vals[n][i];
    }
#pragma unroll
    for (int off = 32; off > 0; off >>= 1) s += __shfl_down(s, off);
    if (lane == 0) wsumS[n][wv] = s;
  }
  __syncthreads();
#pragma unroll
  for (int n = 0; n < N; ++n) {
    const float inv =
        1.0f / (wsumS[n][0] + wsumS[n][1] + wsumS[n][2] + wsumS[n][3] + 1e-6f);
#pragma unroll
    for (int i = 0; i < 4; ++i)
      fs[n][threadIdx.x + i * 256] = vals[n][i] * inv;
  }
  __syncthreads();

  // ---- main: issue all 16 nontemporal loads, then consume ----
  const int ch0 = cg * CPB + wv * CPW;
  f4 x[CPW][4];
#pragma unroll
  for (int c = 0; c < CPW; ++c) {
    const f4* row = (const f4*)(v + ((size_t)b * C + ch0 + c) * T);
#pragma unroll
    for (int k = 0; k < 4; ++k)
      x[c][k] = __builtin_nontemporal_load(&row[lane + 64 * k]);
  }

  const f4* w0 = (const f4*)(&fs[0][0]);
  const f4* w1 = (const f4*)(&fs[1][0]);
  const f4* w2 = (const f4*)(&fs[2][0]);

  float acc[CPW][N];
#pragma unroll
  for (int c = 0; c < CPW; ++c)
#pragma unroll
    for (int n = 0; n < N; ++n) acc[c][n] = 0.0f;

#pragma unroll
  for (int k = 0; k < 4; ++k) {
    const f4 q0 = w0[lane + 64 * k];
    const f4 q1 = w1[lane + 64 * k];
    const f4 q2 = w2[lane + 64 * k];
#pragma unroll
    for (int c = 0; c < CPW; ++c) {
      acc[c][0] += dot4(x[c][k], q0);
      acc[c][1] += dot4(x[c][k], q1);
      acc[c][2] += dot4(x[c][k], q2);
    }
  }

  // ---- epilogue: 12 independent wave reductions, lane 0 stores ----
#pragma unroll
  for (int c = 0; c < CPW; ++c)
#pragma unroll
    for (int n = 0; n < N; ++n) acc[c][n] = wred(acc[c][n]);

  if (lane == 0) {
#pragma unroll
    for (int c = 0; c < CPW; ++c) {
      float* o = out + ((size_t)b * C + ch0 + c) * N;
      o[0] = acc[c][0];
      o[1] = acc[c][1];
      o[2] = acc[c][2];
    }
  }
}

// ---------------------------------------------------------------------------
extern "C" void kernel_launch(void* const* d_in, const int* in_sizes, int n_in,
                              void* d_out, int out_size, void* d_ws,
                              size_t ws_size, hipStream_t stream) {
  const float* video = (const float*)d_in[0];   // (B, C, T, 1, 1) fp32
  const int* length = (const int*)d_in[1];      // (B,) int32
  const float* center = (const float*)d_in[2];  // (N,) fp32
  // d_in[3] = delta (unused by reference)
  const float* gamma_ = (const float*)d_in[4];  // (N,) fp32
  float* out = (float*)d_out;                   // (B, C*N) fp32

  tsf_fused<<<B * (C / CPB), 256, 0, stream>>>(video, length, center, gamma_,
                                               out);
}